// Round 10
// baseline (547.360 us; speedup 1.0000x reference)
//
#include <hip/hip_runtime.h>

typedef __bf16 bf16_t;
typedef __bf16 bf16x2 __attribute__((ext_vector_type(2)));
typedef __bf16 bf16x8 __attribute__((ext_vector_type(8)));
typedef float f32x4 __attribute__((ext_vector_type(4)));

#define NL 3
#define HD 128
#define ROWS 32
#define STR 136          // 128 data cols + 8 padding cols that hold bf16(x) (D_IN==8!)
#define THREADS 256
#define BATCH 262144
#define NBLK (BATCH / ROWS)   // 8192

// ws (d_ws) layout in bf16 elements: weights pre-swizzled into MFMA B-fragment order
#define SW_OFF 0                 // [ct=8][lane=64][j=8]                       = 4096
#define U_OFF  4096              // [l=3][g=4][ct=8][lane=64][j=8]             = 49152
#define W_OFF  53248             // [l=3][g=4][ct=8][kc=4][lane=64][j=8]       = 196608
#define WS_ELEMS 249856          // total bf16 elems (499712 bytes)

#define MFMA(a, b, c) __builtin_amdgcn_mfma_f32_16x16x32_bf16((a), (b), (c), 0, 0, 0)

// 3-4 VALU activations (saturating limits exact: exp2->inf->rcp->0)
#define LOG2E 1.4426950408889634f
__device__ __forceinline__ float sigm(float v) {
    return __builtin_amdgcn_rcpf(1.f + __builtin_amdgcn_exp2f(-LOG2E * v));
}
__device__ __forceinline__ float sigmn(float v) {  // = 1 - sigm(v) = sigm(-v)
    return __builtin_amdgcn_rcpf(1.f + __builtin_amdgcn_exp2f(LOG2E * v));
}
__device__ __forceinline__ float tanh_f(float v) {
    return 1.f - 2.f * __builtin_amdgcn_rcpf(__builtin_amdgcn_exp2f((2.f * LOG2E) * v) + 1.f);
}

// ---------------- prep: swizzle f32 weights into bf16 MFMA B-fragment order in ws ----------------
// B-frag layout for mfma_f32_16x16x32_bf16: lane holds B[k = (lane>>4)*8 + j][n = lane&15]
__global__ void dgm_prep(const float* __restrict__ SwW,
                         const float* __restrict__ Uz, const float* __restrict__ Wz,
                         const float* __restrict__ Ug, const float* __restrict__ Wg,
                         const float* __restrict__ Ur, const float* __restrict__ Wr,
                         const float* __restrict__ Uh, const float* __restrict__ Wh,
                         bf16_t* __restrict__ ws) {
    int idx = blockIdx.x * 256 + threadIdx.x;
    if (idx >= WS_ELEMS) return;
    const float* Us[4] = {Uz, Ug, Ur, Uh};
    const float* Wm[4] = {Wz, Wg, Wr, Wh};
    if (idx < U_OFF) {
        int ct = idx >> 9, rem = idx & 511, lane = rem >> 3, j = rem & 7;
        int q = lane >> 4, mm = lane & 15;
        int k = q * 8 + j, n = ct * 16 + mm;
        ws[idx] = (k < 8) ? (bf16_t)SwW[k * HD + n] : (bf16_t)0.f;
    } else if (idx < W_OFF) {
        int t = idx - U_OFF;
        int lg = t >> 12, r2 = t & 4095;
        int l = lg >> 2, g = lg & 3;
        int ct = r2 >> 9, rem = r2 & 511, lane = rem >> 3, j = rem & 7;
        int q = lane >> 4, mm = lane & 15;
        int k = q * 8 + j, n = ct * 16 + mm;
        ws[idx] = (k < 8) ? (bf16_t)Us[g][(l * 8 + k) * HD + n] : (bf16_t)0.f;
    } else {
        int t = idx - W_OFF;
        int lg = t >> 14, r2 = t & 16383;
        int l = lg >> 2, g = lg & 3;
        int ct = r2 >> 11, kc = (r2 >> 9) & 3, rem = r2 & 511, lane = rem >> 3, j = rem & 7;
        int q = lane >> 4, mm = lane & 15;
        int k = kc * 32 + q * 8 + j, n = ct * 16 + mm;
        ws[idx] = (bf16_t)Wm[g][(l * HD + k) * HD + n];
    }
}

// ---------------- main fused kernel ----------------
// 256-thread blocks, 32 rows, wave owns column tiles {wv, wv+4}: each A-frag ds_read feeds
// 2 MFMAs. 4 blocks/CU -> 4 independent barrier groups (vs 2): barrier drains overlap.
// Phase plan per layer (2 barriers): P_A(R)->bar ; P_Z ; P_G ; P_H+update ->bar (P_Z/P_G/P_H
// read only LDS stable since the barrier and write only own regs / own-column elements).
__global__ __launch_bounds__(THREADS, 4) void dgm_main(
    const float* __restrict__ x,
    const float* __restrict__ Swb,
    const float* __restrict__ Bz, const float* __restrict__ Bg,
    const float* __restrict__ Br, const float* __restrict__ Bh,
    const float* __restrict__ WfW, const float* __restrict__ WfB,
    const bf16_t* __restrict__ ws,
    float* __restrict__ out) {
    __shared__ __align__(16) bf16_t s_sig[2][ROWS * STR];  // sigma(S) ping-pong; cols 128..135 = bf16(x)
    __shared__ __align__(16) bf16_t s_r[ROWS * STR];       // sigma(S)*R;        cols 128..135 = bf16(x)
    __shared__ float red[ROWS];                            // final-dot reduction

    const int tid = threadIdx.x;
    const int lane = tid & 63;
    const int wv = tid >> 6;           // 0..3
    const int ct0 = wv, ct1 = wv + 4;  // this wave's two column tiles
    const int m = lane & 15, q = lane >> 4;
    const int rb = blockIdx.x * ROWS;
    const int c0 = ct0 * 16 + m, c1 = ct1 * 16 + m;
    const int fo0 = (ct0 * 64 + lane) * 8, fo1 = (ct1 * 64 + lane) * 8;

    if (tid < ROWS) red[tid] = 0.f;

    // stage bf16(x) into the padding columns (one element per thread: 32 rows x 8)
    {
        int r = tid >> 3, j = tid & 7;
        bf16_t xv = (bf16_t)x[(size_t)(rb + r) * 8 + j];
        s_sig[0][r * STR + 128 + j] = xv;
        s_sig[1][r * STR + 128 + j] = xv;
        s_r[r * STR + 128 + j] = xv;
    }
    __syncthreads();

    bf16x2 svp[2][2][2];  // sigma(S) at this thread's 16 elements [rt][ch][pair] (8 VGPRs)

    // ---- init: S0 = x@Sw + b (x-chunk A-frag at +128, in-row for all quads)
    {
        const float swb0 = Swb[c0], swb1 = Swb[c1];
        bf16x8 fS0 = *(const bf16x8*)(ws + SW_OFF + fo0);
        bf16x8 fS1 = *(const bf16x8*)(ws + SW_OFF + fo1);
#pragma unroll
        for (int rt = 0; rt < 2; rt++) {
            bf16x8 a = *(const bf16x8*)(&s_sig[0][(rt * 16 + m) * STR + 128]);
            f32x4 a0 = {0.f, 0.f, 0.f, 0.f}, a1 = {0.f, 0.f, 0.f, 0.f};
            a0 = MFMA(a, fS0, a0);
            a1 = MFMA(a, fS1, a1);
#pragma unroll
            for (int i = 0; i < 4; i++) {
                int r = rt * 16 + q * 4 + i;
                bf16_t s0 = (bf16_t)sigm(a0[i] + swb0);
                bf16_t s1 = (bf16_t)sigm(a1[i] + swb1);
                svp[rt][0][i >> 1][i & 1] = s0;
                svp[rt][1][i >> 1][i & 1] = s1;
                s_sig[0][r * STR + c0] = s0;
                s_sig[0][r * STR + c1] = s1;
            }
        }
    }
    __syncthreads();

#pragma unroll 1
    for (int l = 0; l < NL; l++) {
        const int cur = l & 1, nxt = cur ^ 1;
        const bf16_t* wb = ws + W_OFF + (size_t)l * 4 * 16384;
        const bf16_t* ub = ws + U_OFF + (size_t)l * 4 * 4096;

        // ---- P_A: R -> s_r   (10 frags: ct-pair of gate 2)
        {
            bf16x8 fU0 = *(const bf16x8*)(ub + 2 * 4096 + fo0);
            bf16x8 fU1 = *(const bf16x8*)(ub + 2 * 4096 + fo1);
            bf16x8 fW0[4], fW1[4];
#pragma unroll
            for (int kc = 0; kc < 4; kc++) {
                fW0[kc] = *(const bf16x8*)(wb + 2 * 16384 + (ct0 * 4 + kc) * 512 + lane * 8);
                fW1[kc] = *(const bf16x8*)(wb + 2 * 16384 + (ct1 * 4 + kc) * 512 + lane * 8);
            }
            const float br0 = Br[l * HD + c0], br1 = Br[l * HD + c1];
#pragma unroll
            for (int rt = 0; rt < 2; rt++) {
                const bf16_t* abase = &s_sig[cur][(rt * 16 + m) * STR];
                f32x4 a0 = {0.f, 0.f, 0.f, 0.f}, a1 = {0.f, 0.f, 0.f, 0.f};
#pragma unroll
                for (int kc = 0; kc < 4; kc++) {
                    bf16x8 a = *(const bf16x8*)(abase + kc * 32 + q * 8);
                    a0 = MFMA(a, fW0[kc], a0);
                    a1 = MFMA(a, fW1[kc], a1);
                }
                {
                    bf16x8 a = *(const bf16x8*)(abase + 128);  // x chunk
                    a0 = MFMA(a, fU0, a0);
                    a1 = MFMA(a, fU1, a1);
                }
#pragma unroll
                for (int i = 0; i < 4; i++) {
                    int r = rt * 16 + q * 4 + i;
                    s_r[r * STR + c0] = (bf16_t)(sigm(a0[i] + br0) * (float)svp[rt][0][i >> 1][i & 1]);
                    s_r[r * STR + c1] = (bf16_t)(sigm(a1[i] + br1) * (float)svp[rt][1][i >> 1][i & 1]);
                }
            }
        }
        __syncthreads();

        bf16x2 t1p[2][2][2];  // z*sigma(S) packed (8 VGPRs)
        bf16x2 ogp[2][2][2];  // 1-G packed (8 VGPRs)

        // ---- P_Z: z*sigma(S) -> t1p (regs only; no barrier needed)
        {
            bf16x8 fU0 = *(const bf16x8*)(ub + 0 * 4096 + fo0);
            bf16x8 fU1 = *(const bf16x8*)(ub + 0 * 4096 + fo1);
            bf16x8 fW0[4], fW1[4];
#pragma unroll
            for (int kc = 0; kc < 4; kc++) {
                fW0[kc] = *(const bf16x8*)(wb + 0 * 16384 + (ct0 * 4 + kc) * 512 + lane * 8);
                fW1[kc] = *(const bf16x8*)(wb + 0 * 16384 + (ct1 * 4 + kc) * 512 + lane * 8);
            }
            const float bz0 = Bz[l * HD + c0], bz1 = Bz[l * HD + c1];
#pragma unroll
            for (int rt = 0; rt < 2; rt++) {
                const bf16_t* abase = &s_sig[cur][(rt * 16 + m) * STR];
                f32x4 a0 = {0.f, 0.f, 0.f, 0.f}, a1 = {0.f, 0.f, 0.f, 0.f};
#pragma unroll
                for (int kc = 0; kc < 4; kc++) {
                    bf16x8 a = *(const bf16x8*)(abase + kc * 32 + q * 8);
                    a0 = MFMA(a, fW0[kc], a0);
                    a1 = MFMA(a, fW1[kc], a1);
                }
                {
                    bf16x8 a = *(const bf16x8*)(abase + 128);
                    a0 = MFMA(a, fU0, a0);
                    a1 = MFMA(a, fU1, a1);
                }
#pragma unroll
                for (int i = 0; i < 4; i++) {
                    t1p[rt][0][i >> 1][i & 1] = (bf16_t)(sigm(a0[i] + bz0) * (float)svp[rt][0][i >> 1][i & 1]);
                    t1p[rt][1][i >> 1][i & 1] = (bf16_t)(sigm(a1[i] + bz1) * (float)svp[rt][1][i >> 1][i & 1]);
                }
            }
        }

        // ---- P_G: 1-G -> ogp (regs only)
        {
            bf16x8 fU0 = *(const bf16x8*)(ub + 1 * 4096 + fo0);
            bf16x8 fU1 = *(const bf16x8*)(ub + 1 * 4096 + fo1);
            bf16x8 fW0[4], fW1[4];
#pragma unroll
            for (int kc = 0; kc < 4; kc++) {
                fW0[kc] = *(const bf16x8*)(wb + 1 * 16384 + (ct0 * 4 + kc) * 512 + lane * 8);
                fW1[kc] = *(const bf16x8*)(wb + 1 * 16384 + (ct1 * 4 + kc) * 512 + lane * 8);
            }
            const float bg0 = Bg[l * HD + c0], bg1 = Bg[l * HD + c1];
#pragma unroll
            for (int rt = 0; rt < 2; rt++) {
                const bf16_t* abase = &s_sig[cur][(rt * 16 + m) * STR];
                f32x4 a0 = {0.f, 0.f, 0.f, 0.f}, a1 = {0.f, 0.f, 0.f, 0.f};
#pragma unroll
                for (int kc = 0; kc < 4; kc++) {
                    bf16x8 a = *(const bf16x8*)(abase + kc * 32 + q * 8);
                    a0 = MFMA(a, fW0[kc], a0);
                    a1 = MFMA(a, fW1[kc], a1);
                }
                {
                    bf16x8 a = *(const bf16x8*)(abase + 128);
                    a0 = MFMA(a, fU0, a0);
                    a1 = MFMA(a, fU1, a1);
                }
#pragma unroll
                for (int i = 0; i < 4; i++) {
                    ogp[rt][0][i >> 1][i & 1] = (bf16_t)sigmn(a0[i] + bg0);
                    ogp[rt][1][i >> 1][i & 1] = (bf16_t)sigmn(a1[i] + bg1);
                }
            }
        }

        // ---- P_H + state update (reads s_r; writes s_sig[nxt] own elems / final dot)
        {
            bf16x8 fU0 = *(const bf16x8*)(ub + 3 * 4096 + fo0);
            bf16x8 fU1 = *(const bf16x8*)(ub + 3 * 4096 + fo1);
            bf16x8 fW0[4], fW1[4];
#pragma unroll
            for (int kc = 0; kc < 4; kc++) {
                fW0[kc] = *(const bf16x8*)(wb + 3 * 16384 + (ct0 * 4 + kc) * 512 + lane * 8);
                fW1[kc] = *(const bf16x8*)(wb + 3 * 16384 + (ct1 * 4 + kc) * 512 + lane * 8);
            }
            const float bh0 = Bh[l * HD + c0], bh1 = Bh[l * HD + c1];
            const bool last = (l == NL - 1);
            const float wf0 = WfW[c0], wf1 = WfW[c1];
#pragma unroll
            for (int rt = 0; rt < 2; rt++) {
                const bf16_t* abase = &s_r[(rt * 16 + m) * STR];
                f32x4 a0 = {0.f, 0.f, 0.f, 0.f}, a1 = {0.f, 0.f, 0.f, 0.f};
#pragma unroll
                for (int kc = 0; kc < 4; kc++) {
                    bf16x8 a = *(const bf16x8*)(abase + kc * 32 + q * 8);
                    a0 = MFMA(a, fW0[kc], a0);
                    a1 = MFMA(a, fW1[kc], a1);
                }
                {
                    bf16x8 a = *(const bf16x8*)(abase + 128);
                    a0 = MFMA(a, fU0, a0);
                    a1 = MFMA(a, fU1, a1);
                }
#pragma unroll
                for (int i = 0; i < 4; i++) {
                    int r = rt * 16 + q * 4 + i;
                    float h0 = tanh_f(a0[i] + bh0);
                    float h1 = tanh_f(a1[i] + bh1);
                    float sn0 = (float)ogp[rt][0][i >> 1][i & 1] * h0 + (float)t1p[rt][0][i >> 1][i & 1];
                    float sn1 = (float)ogp[rt][1][i >> 1][i & 1] * h1 + (float)t1p[rt][1][i >> 1][i & 1];
                    if (last) {
                        float p0 = sn0 * wf0, p1 = sn1 * wf1;  // fold S3@Wf, S3 stays f32
                        p0 += __shfl_xor(p0, 1);  p1 += __shfl_xor(p1, 1);
                        p0 += __shfl_xor(p0, 2);  p1 += __shfl_xor(p1, 2);
                        p0 += __shfl_xor(p0, 4);  p1 += __shfl_xor(p1, 4);
                        p0 += __shfl_xor(p0, 8);  p1 += __shfl_xor(p1, 8);
                        if (m == 0) atomicAdd(&red[r], p0 + p1);
                    } else {
                        bf16_t s20 = (bf16_t)sigm(sn0);
                        bf16_t s21 = (bf16_t)sigm(sn1);
                        svp[rt][0][i >> 1][i & 1] = s20;
                        svp[rt][1][i >> 1][i & 1] = s21;
                        s_sig[nxt][r * STR + c0] = s20;
                        s_sig[nxt][r * STR + c1] = s21;
                    }
                }
            }
        }
        __syncthreads();
    }

    if (tid < ROWS) out[rb + tid] = red[tid] + WfB[0];
}

extern "C" void kernel_launch(void* const* d_in, const int* in_sizes, int n_in,
                              void* d_out, int out_size, void* d_ws, size_t ws_size,
                              hipStream_t stream) {
    const float* x   = (const float*)d_in[0];
    const float* SwW = (const float*)d_in[1];
    const float* Swb = (const float*)d_in[2];
    const float* Uz  = (const float*)d_in[3];
    const float* Wz  = (const float*)d_in[4];
    const float* Bz  = (const float*)d_in[5];
    const float* Ug  = (const float*)d_in[6];
    const float* Wg  = (const float*)d_in[7];
    const float* Bg  = (const float*)d_in[8];
    const float* Ur  = (const float*)d_in[9];
    const float* Wr  = (const float*)d_in[10];
    const float* Br  = (const float*)d_in[11];
    const float* Uh  = (const float*)d_in[12];
    const float* Wh  = (const float*)d_in[13];
    const float* Bh  = (const float*)d_in[14];
    const float* WfW = (const float*)d_in[15];
    const float* WfB = (const float*)d_in[16];
    bf16_t* ws = (bf16_t*)d_ws;
    float* out = (float*)d_out;

    if (ws_size < (size_t)WS_ELEMS * sizeof(bf16_t)) return;  // need ~500 KB scratch

    dgm_prep<<<(WS_ELEMS + 255) / 256, 256, 0, stream>>>(SwW, Uz, Wz, Ug, Wg, Ur, Wr, Uh, Wh, ws);
    dgm_main<<<NBLK, THREADS, 0, stream>>>(x, Swb, Bz, Bg, Br, Bh, WfW, WfB, ws, out);
}

// Round 11
// 319.483 us; speedup vs baseline: 1.7133x; 1.7133x over previous
//
#include <hip/hip_runtime.h>

typedef __bf16 bf16_t;
typedef __bf16 bf16x2 __attribute__((ext_vector_type(2)));
typedef __bf16 bf16x8 __attribute__((ext_vector_type(8)));
typedef float f32x4 __attribute__((ext_vector_type(4)));

#define NL 3
#define HD 128
#define ROWS 64
#define STR 136          // 128 data cols + 8 padding cols that hold bf16(x) (D_IN==8!)
#define THREADS 512
#define BATCH 262144
#define NBLK (BATCH / ROWS)

// ws (d_ws) layout in bf16 elements: weights pre-swizzled into MFMA B-fragment order
#define SW_OFF 0                 // [ct=8][lane=64][j=8]                       = 4096
#define U_OFF  4096              // [l=3][g=4][ct=8][lane=64][j=8]             = 49152
#define W_OFF  53248             // [l=3][g=4][ct=8][kc=4][lane=64][j=8]       = 196608
#define WS_ELEMS 249856          // total bf16 elems (499712 bytes)

#define MFMA(a, b, c) __builtin_amdgcn_mfma_f32_16x16x32_bf16((a), (b), (c), 0, 0, 0)

// 3-4 VALU activations (saturating limits exact: exp2->inf->rcp->0)
#define LOG2E 1.4426950408889634f
__device__ __forceinline__ float sigm(float v) {
    return __builtin_amdgcn_rcpf(1.f + __builtin_amdgcn_exp2f(-LOG2E * v));
}
__device__ __forceinline__ float sigmn(float v) {  // = 1 - sigm(v) = sigm(-v)
    return __builtin_amdgcn_rcpf(1.f + __builtin_amdgcn_exp2f(LOG2E * v));
}
__device__ __forceinline__ float tanh_f(float v) {
    return 1.f - 2.f * __builtin_amdgcn_rcpf(__builtin_amdgcn_exp2f((2.f * LOG2E) * v) + 1.f);
}

// ---------------- prep: swizzle f32 weights into bf16 MFMA B-fragment order in ws ----------------
// B-frag layout for mfma_f32_16x16x32_bf16: lane holds B[k = (lane>>4)*8 + j][n = lane&15]
__global__ void dgm_prep(const float* __restrict__ SwW,
                         const float* __restrict__ Uz, const float* __restrict__ Wz,
                         const float* __restrict__ Ug, const float* __restrict__ Wg,
                         const float* __restrict__ Ur, const float* __restrict__ Wr,
                         const float* __restrict__ Uh, const float* __restrict__ Wh,
                         bf16_t* __restrict__ ws) {
    int idx = blockIdx.x * 256 + threadIdx.x;
    if (idx >= WS_ELEMS) return;
    const float* Us[4] = {Uz, Ug, Ur, Uh};
    const float* Wm[4] = {Wz, Wg, Wr, Wh};
    if (idx < U_OFF) {
        int ct = idx >> 9, rem = idx & 511, lane = rem >> 3, j = rem & 7;
        int q = lane >> 4, mm = lane & 15;
        int k = q * 8 + j, n = ct * 16 + mm;
        ws[idx] = (k < 8) ? (bf16_t)SwW[k * HD + n] : (bf16_t)0.f;
    } else if (idx < W_OFF) {
        int t = idx - U_OFF;
        int lg = t >> 12, r2 = t & 4095;
        int l = lg >> 2, g = lg & 3;
        int ct = r2 >> 9, rem = r2 & 511, lane = rem >> 3, j = rem & 7;
        int q = lane >> 4, mm = lane & 15;
        int k = q * 8 + j, n = ct * 16 + mm;
        ws[idx] = (k < 8) ? (bf16_t)Us[g][(l * 8 + k) * HD + n] : (bf16_t)0.f;
    } else {
        int t = idx - W_OFF;
        int lg = t >> 14, r2 = t & 16383;
        int l = lg >> 2, g = lg & 3;
        int ct = r2 >> 11, kc = (r2 >> 9) & 3, rem = r2 & 511, lane = rem >> 3, j = rem & 7;
        int q = lane >> 4, mm = lane & 15;
        int k = kc * 32 + q * 8 + j, n = ct * 16 + mm;
        ws[idx] = (bf16_t)Wm[g][(l * HD + k) * HD + n];
    }
}

// ---------------- main fused kernel ----------------
// r9 structure (wave = one 16-col tile; P_A(R) -> bar ; P_ZG ; P_H+update -> bar) plus
// cross-phase weight-fragment prefetch: each phase's 5-10 buffer_loads are issued during the
// PREVIOUS phase's MFMA/epilogue section, so their ~200-cyc L2 latency hides behind the
// transcendental epilogue + barrier drain instead of stalling the phase head.
// Live-set budget: max 15 frags (60 VGPRs) + 24 state regs < 128 unified -> no spill
// (tripwire: WRITE_SIZE >> 4 MB means spill came back; r10's 2-ct variant died that way).
__global__ __launch_bounds__(THREADS, 4) void dgm_main(
    const float* __restrict__ x,
    const float* __restrict__ Swb,
    const float* __restrict__ Bz, const float* __restrict__ Bg,
    const float* __restrict__ Br, const float* __restrict__ Bh,
    const float* __restrict__ WfW, const float* __restrict__ WfB,
    const bf16_t* __restrict__ ws,
    float* __restrict__ out) {
    __shared__ __align__(16) bf16_t s_sig[2][ROWS * STR];  // sigma(S) ping-pong; cols 128..135 = bf16(x)
    __shared__ __align__(16) bf16_t s_r[ROWS * STR];       // sigma(S)*R;        cols 128..135 = bf16(x)
    __shared__ float red[ROWS];                            // final-dot reduction

    const int tid = threadIdx.x;
    const int lane = tid & 63;
    const int ct = tid >> 6;           // wave owns column tile ct (cols ct*16..ct*16+15), all 64 rows
    const int m = lane & 15, q = lane >> 4;
    const int rb = blockIdx.x * ROWS;
    const int c = ct * 16 + m;         // this thread's fixed output column
    const int fragoff = (ct * 64 + lane) * 8;
    const int wfragoff = (ct * 4) * 512 + lane * 8;   // base of this wave's W-frag block (kc stride 512)

    if (tid < ROWS) red[tid] = 0.f;

    // stage bf16(x) into the padding columns (one element per thread)
    {
        int r = tid >> 3, j = tid & 7;
        bf16_t xv = (bf16_t)x[(size_t)(rb + r) * 8 + j];
        s_sig[0][r * STR + 128 + j] = xv;
        s_sig[1][r * STR + 128 + j] = xv;
        s_r[r * STR + 128 + j] = xv;
    }
    __syncthreads();

    bf16x2 svp[4][2];  // sigma(S) at this thread's 16 elements, packed (8 VGPRs)

    // prefetch P_A(R) frags for layer 0 (hidden behind the init matmul below)
    bf16x8 fUr, fWr[4];
    {
        const bf16_t* ub0 = ws + U_OFF;
        const bf16_t* wb0 = ws + W_OFF;
        fUr = *(const bf16x8*)(ub0 + 2 * 4096 + fragoff);
#pragma unroll
        for (int kc = 0; kc < 4; kc++)
            fWr[kc] = *(const bf16x8*)(wb0 + 2 * 16384 + wfragoff + kc * 512);
    }

    // ---- init: S0 = x@Sw + b (x-chunk A-frag at +128, in-row for all quads)
    {
        const float swb = Swb[c];
        bf16x8 fSw = *(const bf16x8*)(ws + SW_OFF + fragoff);
#pragma unroll
        for (int rt = 0; rt < 4; rt++) {
            bf16x8 a = *(const bf16x8*)(&s_sig[0][(rt * 16 + m) * STR + 128]);
            f32x4 acc = {0.f, 0.f, 0.f, 0.f};
            acc = MFMA(a, fSw, acc);
#pragma unroll
            for (int i = 0; i < 4; i++) {
                bf16_t s0 = (bf16_t)sigm(acc[i] + swb);
                svp[rt][i >> 1][i & 1] = s0;
                s_sig[0][(rt * 16 + q * 4 + i) * STR + c] = s0;
            }
        }
    }
    __syncthreads();

#pragma unroll 1
    for (int l = 0; l < NL; l++) {
        const int cur = l & 1, nxt = cur ^ 1;
        const bf16_t* wb = ws + W_OFF + (size_t)l * 4 * 16384;
        const bf16_t* ub = ws + U_OFF + (size_t)l * 4 * 4096;

        f32x4 aR[4];
        // ---- P_A: R matmuls (frags were prefetched last phase)
#pragma unroll
        for (int rt = 0; rt < 4; rt++) {
            const bf16_t* abase = &s_sig[cur][(rt * 16 + m) * STR];
            f32x4 acc = {0.f, 0.f, 0.f, 0.f};
#pragma unroll
            for (int kc = 0; kc < 4; kc++) {
                bf16x8 a = *(const bf16x8*)(abase + kc * 32 + q * 8);
                acc = MFMA(a, fWr[kc], acc);
            }
            {
                bf16x8 a = *(const bf16x8*)(abase + 128);  // x chunk
                acc = MFMA(a, fUr, acc);
            }
            aR[rt] = acc;
        }

        // prefetch P_ZG frags (issue before the R epilogue's transcendental chain)
        bf16x8 fUz = *(const bf16x8*)(ub + 0 * 4096 + fragoff);
        bf16x8 fUg = *(const bf16x8*)(ub + 1 * 4096 + fragoff);
        bf16x8 fWz[4], fWg[4];
#pragma unroll
        for (int kc = 0; kc < 4; kc++) {
            fWz[kc] = *(const bf16x8*)(wb + 0 * 16384 + wfragoff + kc * 512);
            fWg[kc] = *(const bf16x8*)(wb + 1 * 16384 + wfragoff + kc * 512);
        }

        // ---- R epilogue -> s_r
        {
            const float br = Br[l * HD + c];
#pragma unroll
            for (int rt = 0; rt < 4; rt++)
#pragma unroll
                for (int i = 0; i < 4; i++) {
                    int r = rt * 16 + q * 4 + i;
                    float sb = (float)svp[rt][i >> 1][i & 1];
                    s_r[r * STR + c] = (bf16_t)(sigm(aR[rt][i] + br) * sb);
                }
        }
        __syncthreads();

        bf16x2 t1p[4][2];  // z*sigma(S), packed bf16 (8 VGPRs, carried to P_H)
        bf16x2 ogp[4][2];  // 1-G,        packed bf16 (8 VGPRs)

        // ---- P_ZG: Z and G share each A-fragment read
        f32x4 aZ[4], aG[4];
#pragma unroll
        for (int rt = 0; rt < 4; rt++) {
            const bf16_t* abase = &s_sig[cur][(rt * 16 + m) * STR];
            f32x4 az = {0.f, 0.f, 0.f, 0.f}, ag = {0.f, 0.f, 0.f, 0.f};
#pragma unroll
            for (int kc = 0; kc < 4; kc++) {
                bf16x8 a = *(const bf16x8*)(abase + kc * 32 + q * 8);
                az = MFMA(a, fWz[kc], az);
                ag = MFMA(a, fWg[kc], ag);
            }
            {
                bf16x8 a = *(const bf16x8*)(abase + 128);  // x chunk
                az = MFMA(a, fUz, az);
                ag = MFMA(a, fUg, ag);
            }
            aZ[rt] = az;
            aG[rt] = ag;
        }

        // prefetch P_H frags (hide behind ZG epilogue)
        bf16x8 fUh = *(const bf16x8*)(ub + 3 * 4096 + fragoff);
        bf16x8 fWh[4];
#pragma unroll
        for (int kc = 0; kc < 4; kc++)
            fWh[kc] = *(const bf16x8*)(wb + 3 * 16384 + wfragoff + kc * 512);

        // ---- ZG epilogue -> regs only (no barrier needed before P_H)
        {
            const float bz = Bz[l * HD + c], bg = Bg[l * HD + c];
#pragma unroll
            for (int rt = 0; rt < 4; rt++)
#pragma unroll
                for (int i = 0; i < 4; i++) {
                    float sb = (float)svp[rt][i >> 1][i & 1];
                    t1p[rt][i >> 1][i & 1] = (bf16_t)(sigm(aZ[rt][i] + bz) * sb);
                    ogp[rt][i >> 1][i & 1] = (bf16_t)sigmn(aG[rt][i] + bg);
                }
        }

        // ---- P_H matmuls (reads s_r, stable since P_A's barrier)
        f32x4 aH[4];
#pragma unroll
        for (int rt = 0; rt < 4; rt++) {
            const bf16_t* abase = &s_r[(rt * 16 + m) * STR];
            f32x4 acc = {0.f, 0.f, 0.f, 0.f};
#pragma unroll
            for (int kc = 0; kc < 4; kc++) {
                bf16x8 a = *(const bf16x8*)(abase + kc * 32 + q * 8);
                acc = MFMA(a, fWh[kc], acc);
            }
            {
                bf16x8 a = *(const bf16x8*)(abase + 128);  // x chunk
                acc = MFMA(a, fUh, acc);
            }
            aH[rt] = acc;
        }

        // prefetch next layer's P_A(R) frags (hide behind H epilogue + barrier)
        {
            int ln = (l < NL - 1) ? (l + 1) : l;   // clamp: harmless reload on last layer
            const bf16_t* ubn = ws + U_OFF + (size_t)ln * 4 * 4096;
            const bf16_t* wbn = ws + W_OFF + (size_t)ln * 4 * 16384;
            fUr = *(const bf16x8*)(ubn + 2 * 4096 + fragoff);
#pragma unroll
            for (int kc = 0; kc < 4; kc++)
                fWr[kc] = *(const bf16x8*)(wbn + 2 * 16384 + wfragoff + kc * 512);
        }

        // ---- H epilogue + state update (writes s_sig[nxt] own elems / final dot)
        {
            const float bh = Bh[l * HD + c];
            const bool last = (l == NL - 1);
            const float wfc = WfW[c];
#pragma unroll
            for (int rt = 0; rt < 4; rt++)
#pragma unroll
                for (int i = 0; i < 4; i++) {
                    int r = rt * 16 + q * 4 + i;
                    float hh = tanh_f(aH[rt][i] + bh);
                    float sn = (float)ogp[rt][i >> 1][i & 1] * hh + (float)t1p[rt][i >> 1][i & 1];
                    if (last) {
                        float p = sn * wfc;            // fold S3@Wf into epilogue, S3 stays f32
                        p += __shfl_xor(p, 1);
                        p += __shfl_xor(p, 2);
                        p += __shfl_xor(p, 4);
                        p += __shfl_xor(p, 8);
                        if (m == 0) atomicAdd(&red[r], p);
                    } else {
                        bf16_t s2 = (bf16_t)sigm(sn);
                        svp[rt][i >> 1][i & 1] = s2;
                        s_sig[nxt][r * STR + c] = s2;
                    }
                }
        }
        __syncthreads();
    }

    if (tid < ROWS) out[rb + tid] = red[tid] + WfB[0];
}

extern "C" void kernel_launch(void* const* d_in, const int* in_sizes, int n_in,
                              void* d_out, int out_size, void* d_ws, size_t ws_size,
                              hipStream_t stream) {
    const float* x   = (const float*)d_in[0];
    const float* SwW = (const float*)d_in[1];
    const float* Swb = (const float*)d_in[2];
    const float* Uz  = (const float*)d_in[3];
    const float* Wz  = (const float*)d_in[4];
    const float* Bz  = (const float*)d_in[5];
    const float* Ug  = (const float*)d_in[6];
    const float* Wg  = (const float*)d_in[7];
    const float* Bg  = (const float*)d_in[8];
    const float* Ur  = (const float*)d_in[9];
    const float* Wr  = (const float*)d_in[10];
    const float* Br  = (const float*)d_in[11];
    const float* Uh  = (const float*)d_in[12];
    const float* Wh  = (const float*)d_in[13];
    const float* Bh  = (const float*)d_in[14];
    const float* WfW = (const float*)d_in[15];
    const float* WfB = (const float*)d_in[16];
    bf16_t* ws = (bf16_t*)d_ws;
    float* out = (float*)d_out;

    if (ws_size < (size_t)WS_ELEMS * sizeof(bf16_t)) return;  // need ~500 KB scratch

    dgm_prep<<<(WS_ELEMS + 255) / 256, 256, 0, stream>>>(SwW, Uz, Wz, Ug, Wg, Ur, Wr, Uh, Wh, ws);
    dgm_main<<<NBLK, THREADS, 0, stream>>>(x, Swb, Bz, Bg, Br, Bh, WfW, WfB, ws, out);
}

// Round 12
// 287.341 us; speedup vs baseline: 1.9049x; 1.1119x over previous
//
#include <hip/hip_runtime.h>

typedef __bf16 bf16_t;
typedef __bf16 bf16x4 __attribute__((ext_vector_type(4)));
typedef __bf16 bf16x8 __attribute__((ext_vector_type(8)));
typedef float f32x4 __attribute__((ext_vector_type(4)));

#define NL 3
#define HD 128
#define ROWS 64
#define STR 136          // 128 data cols + 8 padding cols that hold bf16(x) (D_IN==8!)
#define THREADS 512
#define BATCH 262144
#define NBLK (BATCH / ROWS)

// ws (d_ws) layout in bf16 elements: weights pre-swizzled into MFMA fragment order.
// Same bits serve as B-frag of W (old) or A-frag of W^T (transposed compute) — identical lane map.
#define SW_OFF 0                 // [ct=8][lane=64][j=8]                       = 4096
#define U_OFF  4096              // [l=3][g=4][ct=8][lane=64][j=8]             = 49152
#define W_OFF  53248             // [l=3][g=4][ct=8][kc=4][lane=64][j=8]       = 196608
#define WS_ELEMS 249856          // total bf16 elems (499712 bytes)

#define MFMA(a, b, c) __builtin_amdgcn_mfma_f32_16x16x32_bf16((a), (b), (c), 0, 0, 0)

// 3-4 VALU activations (saturating limits exact: exp2->inf->rcp->0)
#define LOG2E 1.4426950408889634f
__device__ __forceinline__ float sigm(float v) {
    return __builtin_amdgcn_rcpf(1.f + __builtin_amdgcn_exp2f(-LOG2E * v));
}
__device__ __forceinline__ float sigmn(float v) {  // = 1 - sigm(v) = sigm(-v)
    return __builtin_amdgcn_rcpf(1.f + __builtin_amdgcn_exp2f(LOG2E * v));
}
__device__ __forceinline__ float tanh_f(float v) {
    return 1.f - 2.f * __builtin_amdgcn_rcpf(__builtin_amdgcn_exp2f((2.f * LOG2E) * v) + 1.f);
}

// ---------------- prep: swizzle f32 weights into bf16 MFMA fragment order in ws (unchanged) ----
__global__ void dgm_prep(const float* __restrict__ SwW,
                         const float* __restrict__ Uz, const float* __restrict__ Wz,
                         const float* __restrict__ Ug, const float* __restrict__ Wg,
                         const float* __restrict__ Ur, const float* __restrict__ Wr,
                         const float* __restrict__ Uh, const float* __restrict__ Wh,
                         bf16_t* __restrict__ ws) {
    int idx = blockIdx.x * 256 + threadIdx.x;
    if (idx >= WS_ELEMS) return;
    const float* Us[4] = {Uz, Ug, Ur, Uh};
    const float* Wm[4] = {Wz, Wg, Wr, Wh};
    if (idx < U_OFF) {
        int ct = idx >> 9, rem = idx & 511, lane = rem >> 3, j = rem & 7;
        int q = lane >> 4, mm = lane & 15;
        int k = q * 8 + j, n = ct * 16 + mm;
        ws[idx] = (k < 8) ? (bf16_t)SwW[k * HD + n] : (bf16_t)0.f;
    } else if (idx < W_OFF) {
        int t = idx - U_OFF;
        int lg = t >> 12, r2 = t & 4095;
        int l = lg >> 2, g = lg & 3;
        int ct = r2 >> 9, rem = r2 & 511, lane = rem >> 3, j = rem & 7;
        int q = lane >> 4, mm = lane & 15;
        int k = q * 8 + j, n = ct * 16 + mm;
        ws[idx] = (k < 8) ? (bf16_t)Us[g][(l * 8 + k) * HD + n] : (bf16_t)0.f;
    } else {
        int t = idx - W_OFF;
        int lg = t >> 14, r2 = t & 16383;
        int l = lg >> 2, g = lg & 3;
        int ct = r2 >> 11, kc = (r2 >> 9) & 3, rem = r2 & 511, lane = rem >> 3, j = rem & 7;
        int q = lane >> 4, mm = lane & 15;
        int k = kc * 32 + q * 8 + j, n = ct * 16 + mm;
        ws[idx] = (bf16_t)Wm[g][(l * HD + k) * HD + n];
    }
}

// ---------------- main fused kernel: TRANSPOSED compute  C^T = W^T(A) x S^T(B) ----------------
// Wave ct owns 16 output features (ct*16..+15) for all 64 batch rows (4 batch tiles bt).
// Thread owns (batch = bt*16 + m, features f0..f0+3), f0 = ct*16 + q*4: epilogue writes are ONE
// ds_write_b64 of 4 contiguous bf16 per tile (was 4 scattered b16 -> 4-way conflicts, r9's
// 1.9e7 SQ_LDS_BANK_CONFLICT). B-frag reads of s_sig/s_r have the identical pattern as r9's
// A-frag reads. Phase plan per layer (2 barriers): P_A(R)->bar ; P_ZG ; P_H+update ->bar.
__global__ __launch_bounds__(THREADS, 4) void dgm_main(
    const float* __restrict__ x,
    const float* __restrict__ Swb,
    const float* __restrict__ Bz, const float* __restrict__ Bg,
    const float* __restrict__ Br, const float* __restrict__ Bh,
    const float* __restrict__ WfW, const float* __restrict__ WfB,
    const bf16_t* __restrict__ ws,
    float* __restrict__ out) {
    __shared__ __align__(16) bf16_t s_sig[2][ROWS * STR];  // sigma(S) ping-pong; cols 128..135 = bf16(x)
    __shared__ __align__(16) bf16_t s_r[ROWS * STR];       // sigma(S)*R;        cols 128..135 = bf16(x)
    __shared__ float red[ROWS];                            // final-dot reduction

    const int tid = threadIdx.x;
    const int lane = tid & 63;
    const int ct = tid >> 6;            // wave's feature tile
    const int m = lane & 15, q = lane >> 4;
    const int rb = blockIdx.x * ROWS;
    const int f0 = ct * 16 + q * 4;     // thread's first output feature (4 consecutive)
    const int fragoff = (ct * 64 + lane) * 8;
    const int wfragoff = (ct * 4) * 512 + lane * 8;

    if (tid < ROWS) red[tid] = 0.f;

    // stage bf16(x) into the padding columns (one element per thread)
    {
        int r = tid >> 3, j = tid & 7;
        bf16_t xv = (bf16_t)x[(size_t)(rb + r) * 8 + j];
        s_sig[0][r * STR + 128 + j] = xv;
        s_sig[1][r * STR + 128 + j] = xv;
        s_r[r * STR + 128 + j] = xv;
    }
    __syncthreads();

    bf16x4 svp[4];  // sigma(S) at this thread's 16 elements [bt] (8 VGPRs)

    // ---- init: S0^T = Sw^T @ x^T  (A = Sw frag from ws, B = x from padding cols)
    {
        const f32x4 swb4 = *(const f32x4*)&Swb[f0];
        bf16x8 fSw = *(const bf16x8*)(ws + SW_OFF + fragoff);
#pragma unroll
        for (int bt = 0; bt < 4; bt++) {
            bf16x8 b = *(const bf16x8*)(&s_sig[0][(bt * 16 + m) * STR + 128]);
            f32x4 acc = {0.f, 0.f, 0.f, 0.f};
            acc = MFMA(fSw, b, acc);
            bf16x4 pk;
#pragma unroll
            for (int i = 0; i < 4; i++) pk[i] = (bf16_t)sigm(acc[i] + swb4[i]);
            svp[bt] = pk;
            *(bf16x4*)(&s_sig[0][(bt * 16 + m) * STR + f0]) = pk;
        }
    }
    __syncthreads();

#pragma unroll 1
    for (int l = 0; l < NL; l++) {
        const int cur = l & 1, nxt = cur ^ 1;
        const bf16_t* wb = ws + W_OFF + (size_t)l * 4 * 16384;
        const bf16_t* ub = ws + U_OFF + (size_t)l * 4 * 4096;

        // ---- P_A: R -> s_r  (5 weight frags live)
        {
            bf16x8 fU = *(const bf16x8*)(ub + 2 * 4096 + fragoff);
            bf16x8 fW[4];
#pragma unroll
            for (int kc = 0; kc < 4; kc++)
                fW[kc] = *(const bf16x8*)(wb + 2 * 16384 + wfragoff + kc * 512);
            const f32x4 br4 = *(const f32x4*)&Br[l * HD + f0];
#pragma unroll
            for (int bt = 0; bt < 4; bt++) {
                const bf16_t* bbase = &s_sig[cur][(bt * 16 + m) * STR];
                f32x4 aR = {0.f, 0.f, 0.f, 0.f};
#pragma unroll
                for (int kc = 0; kc < 4; kc++) {
                    bf16x8 b = *(const bf16x8*)(bbase + kc * 32 + q * 8);
                    aR = MFMA(fW[kc], b, aR);
                }
                {
                    bf16x8 b = *(const bf16x8*)(bbase + 128);  // x chunk
                    aR = MFMA(fU, b, aR);
                }
                bf16x4 pk;
#pragma unroll
                for (int i = 0; i < 4; i++)
                    pk[i] = (bf16_t)(sigm(aR[i] + br4[i]) * (float)svp[bt][i]);
                *(bf16x4*)(&s_r[(bt * 16 + m) * STR + f0]) = pk;
            }
        }
        __syncthreads();

        bf16x4 t1p[4];  // z*sigma(S), packed (8 VGPRs, carried to P_H)
        bf16x4 ogp[4];  // 1-G, packed (8 VGPRs)

        // ---- P_ZG: Z and G share each B-fragment read (10 weight frags live; regs only)
        {
            bf16x8 fUz = *(const bf16x8*)(ub + 0 * 4096 + fragoff);
            bf16x8 fUg = *(const bf16x8*)(ub + 1 * 4096 + fragoff);
            bf16x8 fWz[4], fWg[4];
#pragma unroll
            for (int kc = 0; kc < 4; kc++) {
                fWz[kc] = *(const bf16x8*)(wb + 0 * 16384 + wfragoff + kc * 512);
                fWg[kc] = *(const bf16x8*)(wb + 1 * 16384 + wfragoff + kc * 512);
            }
            const f32x4 bz4 = *(const f32x4*)&Bz[l * HD + f0];
            const f32x4 bg4 = *(const f32x4*)&Bg[l * HD + f0];
#pragma unroll
            for (int bt = 0; bt < 4; bt++) {
                const bf16_t* bbase = &s_sig[cur][(bt * 16 + m) * STR];
                f32x4 aZ = {0.f, 0.f, 0.f, 0.f}, aG = {0.f, 0.f, 0.f, 0.f};
#pragma unroll
                for (int kc = 0; kc < 4; kc++) {
                    bf16x8 b = *(const bf16x8*)(bbase + kc * 32 + q * 8);
                    aZ = MFMA(fWz[kc], b, aZ);
                    aG = MFMA(fWg[kc], b, aG);
                }
                {
                    bf16x8 b = *(const bf16x8*)(bbase + 128);  // x chunk
                    aZ = MFMA(fUz, b, aZ);
                    aG = MFMA(fUg, b, aG);
                }
                bf16x4 t1, og;
#pragma unroll
                for (int i = 0; i < 4; i++) {
                    t1[i] = (bf16_t)(sigm(aZ[i] + bz4[i]) * (float)svp[bt][i]);
                    og[i] = (bf16_t)sigmn(aG[i] + bg4[i]);
                }
                t1p[bt] = t1;
                ogp[bt] = og;
            }
        }

        // ---- P_H + state update (reads s_r, stable since P_A's barrier)
        {
            bf16x8 fU = *(const bf16x8*)(ub + 3 * 4096 + fragoff);
            bf16x8 fW[4];
#pragma unroll
            for (int kc = 0; kc < 4; kc++)
                fW[kc] = *(const bf16x8*)(wb + 3 * 16384 + wfragoff + kc * 512);
            const f32x4 bh4 = *(const f32x4*)&Bh[l * HD + f0];
            const bool last = (l == NL - 1);
            const f32x4 wf4 = *(const f32x4*)&WfW[f0];
#pragma unroll
            for (int bt = 0; bt < 4; bt++) {
                const bf16_t* bbase = &s_r[(bt * 16 + m) * STR];
                f32x4 aH = {0.f, 0.f, 0.f, 0.f};
#pragma unroll
                for (int kc = 0; kc < 4; kc++) {
                    bf16x8 b = *(const bf16x8*)(bbase + kc * 32 + q * 8);
                    aH = MFMA(fW[kc], b, aH);
                }
                {
                    bf16x8 b = *(const bf16x8*)(bbase + 128);  // x chunk
                    aH = MFMA(fU, b, aH);
                }
                if (last) {
                    float p = 0.f;
#pragma unroll
                    for (int i = 0; i < 4; i++) {
                        float hh = tanh_f(aH[i] + bh4[i]);
                        float sn = (float)ogp[bt][i] * hh + (float)t1p[bt][i];
                        p += sn * wf4[i];              // fold S3@Wf; S3 stays f32
                    }
                    p += __shfl_xor(p, 16);            // reduce across q (features)
                    p += __shfl_xor(p, 32);
                    if (q == 0) atomicAdd(&red[bt * 16 + m], p);
                } else {
                    bf16x4 pk;
#pragma unroll
                    for (int i = 0; i < 4; i++) {
                        float hh = tanh_f(aH[i] + bh4[i]);
                        float sn = (float)ogp[bt][i] * hh + (float)t1p[bt][i];
                        pk[i] = (bf16_t)sigm(sn);
                    }
                    svp[bt] = pk;
                    *(bf16x4*)(&s_sig[nxt][(bt * 16 + m) * STR + f0]) = pk;
                }
            }
        }
        __syncthreads();
    }

    if (tid < ROWS) out[rb + tid] = red[tid] + WfB[0];
}

extern "C" void kernel_launch(void* const* d_in, const int* in_sizes, int n_in,
                              void* d_out, int out_size, void* d_ws, size_t ws_size,
                              hipStream_t stream) {
    const float* x   = (const float*)d_in[0];
    const float* SwW = (const float*)d_in[1];
    const float* Swb = (const float*)d_in[2];
    const float* Uz  = (const float*)d_in[3];
    const float* Wz  = (const float*)d_in[4];
    const float* Bz  = (const float*)d_in[5];
    const float* Ug  = (const float*)d_in[6];
    const float* Wg  = (const float*)d_in[7];
    const float* Bg  = (const float*)d_in[8];
    const float* Ur  = (const float*)d_in[9];
    const float* Wr  = (const float*)d_in[10];
    const float* Br  = (const float*)d_in[11];
    const float* Uh  = (const float*)d_in[12];
    const float* Wh  = (const float*)d_in[13];
    const float* Bh  = (const float*)d_in[14];
    const float* WfW = (const float*)d_in[15];
    const float* WfB = (const float*)d_in[16];
    bf16_t* ws = (bf16_t*)d_ws;
    float* out = (float*)d_out;

    if (ws_size < (size_t)WS_ELEMS * sizeof(bf16_t)) return;  // need ~500 KB scratch

    dgm_prep<<<(WS_ELEMS + 255) / 256, 256, 0, stream>>>(SwW, Uz, Wz, Ug, Wg, Ur, Wr, Uh, Wh, ws);
    dgm_main<<<NBLK, THREADS, 0, stream>>>(x, Swb, Bz, Bg, Br, Bh, WfW, WfB, ws, out);
}